// Round 6
// baseline (342.258 us; speedup 1.0000x reference)
//
#include <hip/hip_runtime.h>
#include <hip/hip_bf16.h>
#include <hip/hip_cooperative_groups.h>

namespace cg = cooperative_groups;

#define NROWS 4096
#define BSZ   2048
#define DIM   128
#define CB    512            // cooperative grid blocks (needs only 2 blocks/CU)
#define NTASK 4096           // 256 row-strips x 16 col-chunks
#define COOPW (CB * 4)       // coop waves

typedef __bf16 bf16x8 __attribute__((ext_vector_type(8)));
typedef float  f32x4  __attribute__((ext_vector_type(4)));

// ---------------------------------------------------------------------------
// Shared device helpers (used by both the cooperative kernel and the fallback
// multi-kernel path — identical math, identical layout).
// Panel layout (verified round 5): 16B chunk index = p*256 + kt*64 + lk*16 + lrow
// so fragment load for (panel, kt) is zv[p*256 + kt*64 + lane]: 1KB coalesced.
// MFMA C/D layout (verified): col = lane&15, row = (lane>>4)*4 + reg.
// ---------------------------------------------------------------------------
__device__ __forceinline__ void do_prep(int p, int tid,
                                        const float* __restrict__ feats,
                                        const float* __restrict__ labels,
                                        __hip_bfloat16* __restrict__ zbf,
                                        float* __restrict__ y) {
    int r = tid >> 4;                   // row in panel
    int c = tid & 15;                   // 8-elem k-chunk
    int i = p * 16 + r;
    int srow = (i < BSZ) ? i : (i - BSZ);
    int view = (i < BSZ) ? 0 : 1;
    const float* src = feats + ((size_t)srow * 2 + view) * DIM + c * 8;
    float4 v0 = *reinterpret_cast<const float4*>(src);
    float4 v1 = *reinterpret_cast<const float4*>(src + 4);
    float ss = v0.x*v0.x + v0.y*v0.y + v0.z*v0.z + v0.w*v0.w
             + v1.x*v1.x + v1.y*v1.y + v1.z*v1.z + v1.w*v1.w;
    #pragma unroll
    for (int off = 8; off >= 1; off >>= 1) ss += __shfl_xor(ss, off);
    float inv = 1.0f / fmaxf(sqrtf(ss), 1e-12f);
    bf16x8 hz;
    hz[0] = (__bf16)(v0.x * inv); hz[1] = (__bf16)(v0.y * inv);
    hz[2] = (__bf16)(v0.z * inv); hz[3] = (__bf16)(v0.w * inv);
    hz[4] = (__bf16)(v1.x * inv); hz[5] = (__bf16)(v1.y * inv);
    hz[6] = (__bf16)(v1.z * inv); hz[7] = (__bf16)(v1.w * inv);
    ((bf16x8*)zbf)[(size_t)p * 256 + (c >> 2) * 64 + (c & 3) * 16 + r] = hz;
    if (c == 0) y[i] = labels[srow];
}

__device__ __forceinline__ void do_label_range(int tid,
                                               const float* __restrict__ labels,
                                               float* __restrict__ scal,
                                               float* __restrict__ out,
                                               float* smn, float* smx) {
    float mn = 1e30f, mx = -1e30f;
    for (int k = tid; k < BSZ; k += 256) {
        float v = labels[k];
        mn = fminf(mn, v); mx = fmaxf(mx, v);
    }
    #pragma unroll
    for (int off = 32; off >= 1; off >>= 1) {
        mn = fminf(mn, __shfl_xor(mn, off));
        mx = fmaxf(mx, __shfl_xor(mx, off));
    }
    if ((tid & 63) == 0) { smn[tid >> 6] = mn; smx[tid >> 6] = mx; }
    __syncthreads();
    if (tid == 0) {
        mn = fminf(fminf(smn[0], smn[1]), fminf(smn[2], smn[3]));
        mx = fmaxf(fmaxf(smx[0], smx[1]), fmaxf(smx[2], smx[3]));
        scal[1] = mx - mn;
        out[0]  = 0.0f;
    }
}

// min of a 16x256 Gram strip (strip = row panel, by = 256-col chunk)
__device__ __forceinline__ float gram_task_min(int strip, int by, int lane,
                                               const bf16x8* __restrict__ zv) {
    bf16x8 afr[4];
    #pragma unroll
    for (int kt = 0; kt < 4; ++kt)
        afr[kt] = zv[(size_t)strip * 256 + kt * 64 + lane];
    float mymin = 1e30f;
    #pragma unroll
    for (int u = 0; u < 16; ++u) {
        int p = by * 16 + u;
        bf16x8 bfr[4];
        #pragma unroll
        for (int kt = 0; kt < 4; ++kt)
            bfr[kt] = zv[(size_t)p * 256 + kt * 64 + lane];
        f32x4 acc = {0.f, 0.f, 0.f, 0.f};
        #pragma unroll
        for (int kt = 0; kt < 4; ++kt)
            acc = __builtin_amdgcn_mfma_f32_16x16x32_bf16(afr[kt], bfr[kt], acc, 0, 0, 0);
        #pragma unroll
        for (int j = 0; j < 4; ++j) mymin = fminf(mymin, acc[j]);
    }
    return mymin;
}

// full elementwise pass for one 16x256 Gram strip -> partial (E,S1,S2) stores
__device__ __forceinline__ void gram_task_main(int strip, int by, int lane,
                                               const bf16x8* __restrict__ zv,
                                               const float* __restrict__ y,
                                               float invdz, float invdy,
                                               float* __restrict__ partE,
                                               float* __restrict__ partS1,
                                               float* __restrict__ partS2) {
    int lrow = lane & 15, lk = lane >> 4;
    const float invT = 1.0f / 0.07f;
    bf16x8 afr[4];
    #pragma unroll
    for (int kt = 0; kt < 4; ++kt)
        afr[kt] = zv[(size_t)strip * 256 + kt * 64 + lane];
    int myrow0 = strip * 16 + lk * 4;
    float yr[4];
    #pragma unroll
    for (int j = 0; j < 4; ++j) yr[j] = y[myrow0 + j];

    float accE[4] = {0.f,0.f,0.f,0.f};
    float acc1[4] = {0.f,0.f,0.f,0.f};
    float acc2[4] = {0.f,0.f,0.f,0.f};
    int c0 = by * 256;
    #pragma unroll
    for (int u = 0; u < 16; ++u) {
        int p = by * 16 + u;
        bf16x8 bfr[4];
        #pragma unroll
        for (int kt = 0; kt < 4; ++kt)
            bfr[kt] = zv[(size_t)p * 256 + kt * 64 + lane];
        float yc = y[c0 + u * 16 + lrow];
        f32x4 acc = {0.f, 0.f, 0.f, 0.f};
        #pragma unroll
        for (int kt = 0; kt < 4; ++kt)
            acc = __builtin_amdgcn_mfma_f32_16x16x32_bf16(afr[kt], bfr[kt], acc, 0, 0, 0);
        int mycol = c0 + u * 16 + lrow;
        #pragma unroll
        for (int j = 0; j < 4; ++j) {
            float s  = acc[j];
            bool  on = (myrow0 + j != mycol);
            float dy = yr[j] - yc;
            float w  = __expf(-2.0f * dy * dy);          // sigma=0.5
            float dyn = fabsf(dy) * invdy;
            float dzn = (1.0f - s) * invdz;
            float uu  = fminf(fmaxf(dzn - dyn, -1.0f), 1.0f);
            float wh  = (uu > 0.0f) ? (1.0f + w * uu) : (1.0f - (1.0f - w) * uu);
            float sT  = s * invT;
            float e   = on ? __expf(sT) : 0.0f;
            float whm = on ? wh : 0.0f;
            accE[j] += e;
            acc1[j] += whm;
            acc2[j] += whm * wh * sT;
        }
    }
    #pragma unroll
    for (int j = 0; j < 4; ++j) {
        #pragma unroll
        for (int off = 1; off < 16; off <<= 1) {
            accE[j] += __shfl_xor(accE[j], off);
            acc1[j] += __shfl_xor(acc1[j], off);
            acc2[j] += __shfl_xor(acc2[j], off);
        }
    }
    if (lrow == 0) {
        size_t base = (size_t)by * NROWS + myrow0;
        f32x4 vE = {accE[0], accE[1], accE[2], accE[3]};
        f32x4 v1 = {acc1[0], acc1[1], acc1[2], acc1[3]};
        f32x4 v2 = {acc2[0], acc2[1], acc2[2], acc2[3]};
        *(f32x4*)&partE[base]  = vE;
        *(f32x4*)&partS1[base] = v1;
        *(f32x4*)&partS2[base] = v2;
    }
}

__device__ __forceinline__ void do_rowred(int blk, int tid,
                                          const float* __restrict__ partE,
                                          const float* __restrict__ partS1,
                                          const float* __restrict__ partS2,
                                          float* __restrict__ out, float* wred) {
    int r = blk * 256 + tid;
    float E = 0.f, S1 = 0.f, S2 = 0.f;
    #pragma unroll
    for (int c = 0; c < 16; ++c) {
        size_t o = (size_t)c * NROWS + r;
        E  += partE[o];
        S1 += partS1[o];
        S2 += partS2[o];
    }
    float mlpp = (S2 - logf(E + 1e-8f) * S1) / (S1 + 1e-8f);
    float sum  = -mlpp;
    #pragma unroll
    for (int off = 32; off >= 1; off >>= 1) sum += __shfl_xor(sum, off);
    if ((tid & 63) == 0) wred[tid >> 6] = sum;
    __syncthreads();
    if (tid == 0)
        atomicAdd(out, (wred[0] + wred[1] + wred[2] + wred[3]) * (1.0f / NROWS));
}

// ---------------------------------------------------------------------------
// Single cooperative kernel: prep -> sync -> triangle smin -> sync -> main
// -> sync -> rowred. 512 blocks (2/CU), VGPR capped at 128 by launch bounds;
// no accumulators held across grid.sync (phase B recomputes its Gram strip).
// ---------------------------------------------------------------------------
__global__ __launch_bounds__(256, 4) void k_coop(const float* __restrict__ feats,
                                                 const float* __restrict__ labels,
                                                 __hip_bfloat16* __restrict__ zbf,
                                                 float* __restrict__ y,
                                                 float* __restrict__ scal,
                                                 float* __restrict__ bmin,
                                                 float* __restrict__ partE,
                                                 float* __restrict__ partS1,
                                                 float* __restrict__ partS2,
                                                 float* __restrict__ out) {
    cg::grid_group grid = cg::this_grid();
    const int tid  = threadIdx.x;
    const int bid  = blockIdx.x;
    const int wv   = tid >> 6;
    const int lane = tid & 63;
    const bf16x8* zv = (const bf16x8*)zbf;
    __shared__ float wred[4];
    __shared__ float smx[4];
    __shared__ float s_smin;

    // phase 0: prep (blocks 0..255, one panel each); block 0 also label range
    if (bid < 256) do_prep(bid, tid, feats, labels, zbf, y);
    if (bid == 0)  do_label_range(tid, labels, scal, out, wred, smx);

    grid.sync();

    // phase A: smin over upper triangle (S symmetric bitwise)
    float mymin = 1e30f;
    for (int t = bid * 4 + wv; t < NTASK; t += COOPW) {
        int strip = t & 255, by = t >> 8;
        if (by * 256 + 255 >= strip * 16)
            mymin = fminf(mymin, gram_task_min(strip, by, lane, zv));
    }
    #pragma unroll
    for (int off = 32; off >= 1; off >>= 1)
        mymin = fminf(mymin, __shfl_xor(mymin, off));
    if (lane == 0) wred[wv] = mymin;
    __syncthreads();
    if (tid == 0)
        bmin[bid] = fminf(fminf(wred[0], wred[1]), fminf(wred[2], wred[3]));

    grid.sync();

    // phase B: reduce bmin -> smin; fused elementwise main pass
    float m = fminf(bmin[tid], bmin[256 + tid]);
    #pragma unroll
    for (int off = 32; off >= 1; off >>= 1) m = fminf(m, __shfl_xor(m, off));
    if (lane == 0) wred[wv] = m;
    __syncthreads();
    if (tid == 0)
        s_smin = fminf(fminf(wred[0], wred[1]), fminf(wred[2], wred[3]));
    __syncthreads();
    float invdz = 1.0f / ((1.0f - s_smin) + 1e-8f);
    float invdy = 1.0f / (scal[1] + 1e-8f);
    for (int t = bid * 4 + wv; t < NTASK; t += COOPW) {
        int strip = t & 255, by = t >> 8;
        gram_task_main(strip, by, lane, zv, y, invdz, invdy, partE, partS1, partS2);
    }

    grid.sync();

    // phase C: row reduce + loss (blocks 0..15)
    if (bid < 16) do_rowred(bid, tid, partE, partS1, partS2, out, wred);
}

// ---------------------------------------------------------------------------
// Fallback path (4 dispatches) — used iff the cooperative launch is rejected.
// ---------------------------------------------------------------------------
__global__ __launch_bounds__(256) void k_prep(const float* __restrict__ feats,
                                              const float* __restrict__ labels,
                                              __hip_bfloat16* __restrict__ zbf,
                                              float* __restrict__ y,
                                              float* __restrict__ scal,
                                              float* __restrict__ out) {
    __shared__ float smn[4], smx[4];
    do_prep(blockIdx.x, threadIdx.x, feats, labels, zbf, y);
    if (blockIdx.x == 0) do_label_range(threadIdx.x, labels, scal, out, smn, smx);
}

__global__ __launch_bounds__(256) void k_smin(const __hip_bfloat16* __restrict__ zbf,
                                              float* __restrict__ bmin) {
    int wv = threadIdx.x >> 6, lane = threadIdx.x & 63;
    int strip = blockIdx.x * 4 + wv;
    float mymin = (blockIdx.y * 256 + 255 >= strip * 16)
                ? gram_task_min(strip, blockIdx.y, lane, (const bf16x8*)zbf)
                : 1e30f;
    #pragma unroll
    for (int off = 32; off >= 1; off >>= 1)
        mymin = fminf(mymin, __shfl_xor(mymin, off));
    __shared__ float wmin[4];
    if (lane == 0) wmin[wv] = mymin;
    __syncthreads();
    if (threadIdx.x == 0)
        bmin[blockIdx.y * 64 + blockIdx.x] =
            fminf(fminf(wmin[0], wmin[1]), fminf(wmin[2], wmin[3]));
}

__global__ __launch_bounds__(256) void k_main(const __hip_bfloat16* __restrict__ zbf,
                                              const float* __restrict__ y,
                                              const float* __restrict__ scal,
                                              const float* __restrict__ bmin,
                                              float* __restrict__ partE,
                                              float* __restrict__ partS1,
                                              float* __restrict__ partS2) {
    int tid = threadIdx.x, wv = tid >> 6, lane = tid & 63;
    __shared__ float wred[4];
    __shared__ float s_smin;
    float m = 1e30f;
    #pragma unroll
    for (int c = 0; c < 4; ++c) m = fminf(m, bmin[c * 256 + tid]);
    #pragma unroll
    for (int off = 32; off >= 1; off >>= 1) m = fminf(m, __shfl_xor(m, off));
    if (lane == 0) wred[wv] = m;
    __syncthreads();
    if (tid == 0)
        s_smin = fminf(fminf(wred[0], wred[1]), fminf(wred[2], wred[3]));
    __syncthreads();
    float invdz = 1.0f / ((1.0f - s_smin) + 1e-8f);
    float invdy = 1.0f / (scal[1] + 1e-8f);
    int strip = blockIdx.x * 4 + wv;
    gram_task_main(strip, blockIdx.y, lane, (const bf16x8*)zbf, y,
                   invdz, invdy, partE, partS1, partS2);
}

__global__ __launch_bounds__(256) void k_rowred(const float* __restrict__ partE,
                                                const float* __restrict__ partS1,
                                                const float* __restrict__ partS2,
                                                float* __restrict__ out) {
    __shared__ float wred[4];
    do_rowred(blockIdx.x, threadIdx.x, partE, partS1, partS2, out, wred);
}

extern "C" void kernel_launch(void* const* d_in, const int* in_sizes, int n_in,
                              void* d_out, int out_size, void* d_ws, size_t ws_size,
                              hipStream_t stream) {
    const float* feats  = (const float*)d_in[0];   // (2048, 2, 128) f32
    const float* labels = (const float*)d_in[1];   // (2048, 1) f32
    float* out = (float*)d_out;

    char* ws = (char*)d_ws;
    __hip_bfloat16* zbf = (__hip_bfloat16*)ws;                  // 1 MB
    float* y      = (float*)(ws + (1 << 20));                   // 16 KB
    float* scal   = y + NROWS;
    float* bmin   = scal + 16;                                  // 4 KB
    float* partE  = bmin + 1024;                                // 256 KB
    float* partS1 = partE  + 16 * NROWS;
    float* partS2 = partS1 + 16 * NROWS;

    void* args[] = {(void*)&feats, (void*)&labels, (void*)&zbf, (void*)&y,
                    (void*)&scal, (void*)&bmin, (void*)&partE, (void*)&partS1,
                    (void*)&partS2, (void*)&out};
    hipError_t err = hipLaunchCooperativeKernel((const void*)k_coop, dim3(CB),
                                                dim3(256), args, 0, stream);
    if (err != hipSuccess) {
        (void)hipGetLastError();   // clear sticky error; use fallback pipeline
        k_prep  <<<NROWS / 16, 256, 0, stream>>>(feats, labels, zbf, y, scal, out);
        dim3 g(64, 16);
        k_smin  <<<g, 256, 0, stream>>>(zbf, bmin);
        k_main  <<<g, 256, 0, stream>>>(zbf, y, scal, bmin, partE, partS1, partS2);
        k_rowred<<<16, 256, 0, stream>>>(partE, partS1, partS2, out);
    }
}

// Round 7
// 91.797 us; speedup vs baseline: 3.7284x; 3.7284x over previous
//
#include <hip/hip_runtime.h>
#include <hip/hip_bf16.h>

#define NROWS 4096
#define BSZ   2048
#define DIM   128

typedef __bf16 bf16x8 __attribute__((ext_vector_type(8)));
typedef float  f32x4  __attribute__((ext_vector_type(4)));

// ---------------------------------------------------------------------------
// Panel layout (verified round 5): 16B chunk index = p*256 + kt*64 + lk*16 + lrow
// so fragment load for (panel p, k-chunk kt) is zv[p*256 + kt*64 + lane]:
// one fully-coalesced 1KB load per wave.
// MFMA C/D layout (verified): col = lane&15, row = (lane>>4)*4 + reg.
// ---------------------------------------------------------------------------
__device__ __forceinline__ void do_prep(int p, int tid,
                                        const float* __restrict__ feats,
                                        const float* __restrict__ labels,
                                        __hip_bfloat16* __restrict__ zbf,
                                        float* __restrict__ y) {
    int r = tid >> 4;                   // row in panel
    int c = tid & 15;                   // 8-elem k-chunk
    int i = p * 16 + r;
    int srow = (i < BSZ) ? i : (i - BSZ);
    int view = (i < BSZ) ? 0 : 1;
    const float* src = feats + ((size_t)srow * 2 + view) * DIM + c * 8;
    float4 v0 = *reinterpret_cast<const float4*>(src);
    float4 v1 = *reinterpret_cast<const float4*>(src + 4);
    float ss = v0.x*v0.x + v0.y*v0.y + v0.z*v0.z + v0.w*v0.w
             + v1.x*v1.x + v1.y*v1.y + v1.z*v1.z + v1.w*v1.w;
    #pragma unroll
    for (int off = 8; off >= 1; off >>= 1) ss += __shfl_xor(ss, off);
    float inv = 1.0f / fmaxf(sqrtf(ss), 1e-12f);
    bf16x8 hz;
    hz[0] = (__bf16)(v0.x * inv); hz[1] = (__bf16)(v0.y * inv);
    hz[2] = (__bf16)(v0.z * inv); hz[3] = (__bf16)(v0.w * inv);
    hz[4] = (__bf16)(v1.x * inv); hz[5] = (__bf16)(v1.y * inv);
    hz[6] = (__bf16)(v1.z * inv); hz[7] = (__bf16)(v1.w * inv);
    ((bf16x8*)zbf)[(size_t)p * 256 + (c >> 2) * 64 + (c & 3) * 16 + r] = hz;
    if (c == 0) y[i] = labels[srow];
}

// min of a 16x256 Gram strip (strip = row panel, by = 256-col chunk)
__device__ __forceinline__ float gram_task_min(int strip, int by, int lane,
                                               const bf16x8* __restrict__ zv) {
    bf16x8 afr[4];
    #pragma unroll
    for (int kt = 0; kt < 4; ++kt)
        afr[kt] = zv[(size_t)strip * 256 + kt * 64 + lane];
    float mymin = 1e30f;
    #pragma unroll
    for (int u = 0; u < 16; ++u) {
        int p = by * 16 + u;
        bf16x8 bfr[4];
        #pragma unroll
        for (int kt = 0; kt < 4; ++kt)
            bfr[kt] = zv[(size_t)p * 256 + kt * 64 + lane];
        f32x4 acc = {0.f, 0.f, 0.f, 0.f};
        #pragma unroll
        for (int kt = 0; kt < 4; ++kt)
            acc = __builtin_amdgcn_mfma_f32_16x16x32_bf16(afr[kt], bfr[kt], acc, 0, 0, 0);
        #pragma unroll
        for (int j = 0; j < 4; ++j) mymin = fminf(mymin, acc[j]);
    }
    return mymin;
}

// full elementwise pass for one 16x256 Gram strip -> partial (E,S1,S2) stores
__device__ __forceinline__ void gram_task_main(int strip, int by, int lane,
                                               const bf16x8* __restrict__ zv,
                                               const float* __restrict__ y,
                                               float invdz, float invdy,
                                               float* __restrict__ partE,
                                               float* __restrict__ partS1,
                                               float* __restrict__ partS2) {
    int lrow = lane & 15, lk = lane >> 4;
    const float invT = 1.0f / 0.07f;
    bf16x8 afr[4];
    #pragma unroll
    for (int kt = 0; kt < 4; ++kt)
        afr[kt] = zv[(size_t)strip * 256 + kt * 64 + lane];
    int myrow0 = strip * 16 + lk * 4;
    float yr[4];
    #pragma unroll
    for (int j = 0; j < 4; ++j) yr[j] = y[myrow0 + j];

    float accE[4] = {0.f,0.f,0.f,0.f};
    float acc1[4] = {0.f,0.f,0.f,0.f};
    float acc2[4] = {0.f,0.f,0.f,0.f};
    int c0 = by * 256;
    #pragma unroll
    for (int u = 0; u < 16; ++u) {
        int p = by * 16 + u;
        bf16x8 bfr[4];
        #pragma unroll
        for (int kt = 0; kt < 4; ++kt)
            bfr[kt] = zv[(size_t)p * 256 + kt * 64 + lane];
        float yc = y[c0 + u * 16 + lrow];
        f32x4 acc = {0.f, 0.f, 0.f, 0.f};
        #pragma unroll
        for (int kt = 0; kt < 4; ++kt)
            acc = __builtin_amdgcn_mfma_f32_16x16x32_bf16(afr[kt], bfr[kt], acc, 0, 0, 0);
        int mycol = c0 + u * 16 + lrow;
        #pragma unroll
        for (int j = 0; j < 4; ++j) {
            float s  = acc[j];
            bool  on = (myrow0 + j != mycol);
            float dy = yr[j] - yc;
            float w  = __expf(-2.0f * dy * dy);          // sigma=0.5
            float dyn = fabsf(dy) * invdy;
            float dzn = (1.0f - s) * invdz;
            float uu  = fminf(fmaxf(dzn - dyn, -1.0f), 1.0f);
            float wh  = (uu > 0.0f) ? (1.0f + w * uu) : (1.0f - (1.0f - w) * uu);
            float sT  = s * invT;
            float e   = on ? __expf(sT) : 0.0f;
            float whm = on ? wh : 0.0f;
            accE[j] += e;
            acc1[j] += whm;
            acc2[j] += whm * wh * sT;
        }
    }
    #pragma unroll
    for (int j = 0; j < 4; ++j) {
        #pragma unroll
        for (int off = 1; off < 16; off <<= 1) {
            accE[j] += __shfl_xor(accE[j], off);
            acc1[j] += __shfl_xor(acc1[j], off);
            acc2[j] += __shfl_xor(acc2[j], off);
        }
    }
    if (lrow == 0) {
        size_t base = (size_t)by * NROWS + myrow0;
        f32x4 vE = {accE[0], accE[1], accE[2], accE[3]};
        f32x4 v1 = {acc1[0], acc1[1], acc1[2], acc1[3]};
        f32x4 v2 = {acc2[0], acc2[1], acc2[2], acc2[3]};
        *(f32x4*)&partE[base]  = vE;
        *(f32x4*)&partS1[base] = v1;
        *(f32x4*)&partS2[base] = v2;
    }
}

// ---------------------------------------------------------------------------
// Kernel 1: prep all panels; block 0 also label range + zero out[0].
// ---------------------------------------------------------------------------
__global__ __launch_bounds__(256) void k_prep(const float* __restrict__ feats,
                                              const float* __restrict__ labels,
                                              __hip_bfloat16* __restrict__ zbf,
                                              float* __restrict__ y,
                                              float* __restrict__ scal,
                                              float* __restrict__ out) {
    do_prep(blockIdx.x, threadIdx.x, feats, labels, zbf, y);
    if (blockIdx.x == 0) {
        int tid = threadIdx.x;
        float mn = 1e30f, mx = -1e30f;
        for (int k = tid; k < BSZ; k += 256) {
            float v = labels[k];
            mn = fminf(mn, v); mx = fmaxf(mx, v);
        }
        #pragma unroll
        for (int off = 32; off >= 1; off >>= 1) {
            mn = fminf(mn, __shfl_xor(mn, off));
            mx = fmaxf(mx, __shfl_xor(mx, off));
        }
        __shared__ float smn[4], smx[4];
        if ((tid & 63) == 0) { smn[tid >> 6] = mn; smx[tid >> 6] = mx; }
        __syncthreads();
        if (tid == 0) {
            mn = fminf(fminf(smn[0], smn[1]), fminf(smn[2], smn[3]));
            mx = fmaxf(fmaxf(smx[0], smx[1]), fmaxf(smx[2], smx[3]));
            scal[1] = mx - mn;
            out[0]  = 0.0f;
        }
    }
}

// ---------------------------------------------------------------------------
// Kernel 2: triangle smin. S is bitwise-symmetric (identical fragments, same
// accumulation order), so only tiles with by*256+255 >= strip*16 are needed.
// Skipped blocks still write bmin (+1e30) — ws is poisoned.
// ---------------------------------------------------------------------------
__global__ __launch_bounds__(256) void k_smin(const __hip_bfloat16* __restrict__ zbf,
                                              float* __restrict__ bmin) {
    int wv = threadIdx.x >> 6, lane = threadIdx.x & 63;
    int strip = blockIdx.x * 4 + wv;
    float mymin = (blockIdx.y * 256 + 255 >= strip * 16)
                ? gram_task_min(strip, blockIdx.y, lane, (const bf16x8*)zbf)
                : 1e30f;
    #pragma unroll
    for (int off = 32; off >= 1; off >>= 1)
        mymin = fminf(mymin, __shfl_xor(mymin, off));
    __shared__ float wmin[4];
    if (lane == 0) wmin[wv] = mymin;
    __syncthreads();
    if (threadIdx.x == 0)
        bmin[blockIdx.y * 64 + blockIdx.x] =
            fminf(fminf(wmin[0], wmin[1]), fminf(wmin[2], wmin[3]));
}

// ---------------------------------------------------------------------------
// Kernel 3: main pass; per-block bmin reduce (folded redmin) + fused
// elementwise; per-(chunk,row) partials, plain float4 stores.
// ---------------------------------------------------------------------------
__global__ __launch_bounds__(256) void k_main(const __hip_bfloat16* __restrict__ zbf,
                                              const float* __restrict__ y,
                                              const float* __restrict__ scal,
                                              const float* __restrict__ bmin,
                                              float* __restrict__ partE,
                                              float* __restrict__ partS1,
                                              float* __restrict__ partS2) {
    int tid = threadIdx.x, wv = tid >> 6, lane = tid & 63;
    __shared__ float wred[4];
    __shared__ float s_smin;
    float m = 1e30f;
    #pragma unroll
    for (int c = 0; c < 4; ++c) m = fminf(m, bmin[c * 256 + tid]);
    #pragma unroll
    for (int off = 32; off >= 1; off >>= 1) m = fminf(m, __shfl_xor(m, off));
    if (lane == 0) wred[wv] = m;
    __syncthreads();
    if (tid == 0)
        s_smin = fminf(fminf(wred[0], wred[1]), fminf(wred[2], wred[3]));
    __syncthreads();
    float invdz = 1.0f / ((1.0f - s_smin) + 1e-8f);
    float invdy = 1.0f / (scal[1] + 1e-8f);
    int strip = blockIdx.x * 4 + wv;
    gram_task_main(strip, blockIdx.y, lane, (const bf16x8*)zbf, y,
                   invdz, invdy, partE, partS1, partS2);
}

// ---------------------------------------------------------------------------
// Kernel 4: reduce 16 chunks per row, per-row loss, sum -> out (16 atomics).
// ---------------------------------------------------------------------------
__global__ __launch_bounds__(256) void k_rowred(const float* __restrict__ partE,
                                                const float* __restrict__ partS1,
                                                const float* __restrict__ partS2,
                                                float* __restrict__ out) {
    int tid = threadIdx.x;
    int r = blockIdx.x * 256 + tid;
    float E = 0.f, S1 = 0.f, S2 = 0.f;
    #pragma unroll
    for (int c = 0; c < 16; ++c) {
        size_t o = (size_t)c * NROWS + r;
        E  += partE[o];
        S1 += partS1[o];
        S2 += partS2[o];
    }
    float mlpp = (S2 - logf(E + 1e-8f) * S1) / (S1 + 1e-8f);
    float sum  = -mlpp;
    #pragma unroll
    for (int off = 32; off >= 1; off >>= 1) sum += __shfl_xor(sum, off);
    __shared__ float wred[4];
    if ((tid & 63) == 0) wred[tid >> 6] = sum;
    __syncthreads();
    if (tid == 0)
        atomicAdd(out, (wred[0] + wred[1] + wred[2] + wred[3]) * (1.0f / NROWS));
}

extern "C" void kernel_launch(void* const* d_in, const int* in_sizes, int n_in,
                              void* d_out, int out_size, void* d_ws, size_t ws_size,
                              hipStream_t stream) {
    const float* feats  = (const float*)d_in[0];   // (2048, 2, 128) f32
    const float* labels = (const float*)d_in[1];   // (2048, 1) f32
    float* out = (float*)d_out;

    char* ws = (char*)d_ws;
    __hip_bfloat16* zbf = (__hip_bfloat16*)ws;                  // 1 MB
    float* y      = (float*)(ws + (1 << 20));                   // 16 KB
    float* scal   = y + NROWS;
    float* bmin   = scal + 16;                                  // 4 KB
    float* partE  = bmin + 1024;                                // 256 KB
    float* partS1 = partE  + 16 * NROWS;
    float* partS2 = partS1 + 16 * NROWS;

    k_prep  <<<NROWS / 16, 256, 0, stream>>>(feats, labels, zbf, y, scal, out);
    dim3 g(64, 16);
    k_smin  <<<g, 256, 0, stream>>>(zbf, bmin);
    k_main  <<<g, 256, 0, stream>>>(zbf, y, scal, bmin, partE, partS1, partS2);
    k_rowred<<<16, 256, 0, stream>>>(partE, partS1, partS2, out);
}